// Round 4
// baseline (34.103 us; speedup 1.0000x reference)
//
#include <hip/hip_runtime.h>
#include <hip/hip_bf16.h>

// TaskSpecificReadout: out[n,c] = sum_d x[n,d] * W[tasks[n],c,d] + b[tasks[n],c]
// B=2048, D=1024, T=16, C=128.
// Round 4: fully deterministic, atomic-free 3-stage pipeline.
//   prep:         build per-task offsets + sample index + tile list (ws only).
//   gemm_partial: (ksplit, tile, c-half) blocks load fragments direct from
//                 global, fp32->bf16 in-register, 16x16x32 bf16 MFMA, store
//                 fp32 partial tiles to disjoint ws slots. No atomics.
//   reduce:       sum 4 k-partials in fixed order + bias -> out. Each out
//                 element written exactly once; no read of prior out/ws state.

constexpr int D_DIM = 1024;
constexpr int C_DIM = 128;
constexpr int T_DIM = 16;
constexpr int TM     = 32;              // samples per tile
constexpr int KSPLIT = 4;               // k-splits
constexpr int KCH    = D_DIM / KSPLIT;  // 256 k per block
constexpr int MAX_TILES = 80;           // sum ceil(cnt_t/32) <= 64 + 16 = 80

// ws int layout: [0..16] task offsets, [31] ntiles,
//                [32..111] tile_task, [128..207] tile_m0 (local), [256..2303] idx
// ws float region at byte 16384: partial[tile][kspl][cbz][32][64] fp32

typedef __attribute__((ext_vector_type(8))) short bf16x8;
typedef __attribute__((ext_vector_type(4))) float f32x4;

__device__ inline short f2bf(float f) {
    union { __hip_bfloat16 h; short s; } cv;
    cv.h = __float2bfloat16(f);
    return cv.s;
}

__device__ inline bf16x8 cvt8(float4 a, float4 b) {
    bf16x8 r;
    r[0] = f2bf(a.x); r[1] = f2bf(a.y); r[2] = f2bf(a.z); r[3] = f2bf(a.w);
    r[4] = f2bf(b.x); r[5] = f2bf(b.y); r[6] = f2bf(b.z); r[7] = f2bf(b.w);
    return r;
}

__global__ __launch_bounds__(256) void prep_kernel(const int* __restrict__ tasks,
                                                   int B,
                                                   int* __restrict__ ws_i) {
    __shared__ int cnt[T_DIM];
    __shared__ int cur[T_DIM];
    const int tid = threadIdx.x;
    if (tid < T_DIM) cnt[tid] = 0;
    __syncthreads();
    for (int n = tid; n < B; n += 256) atomicAdd(&cnt[tasks[n]], 1);
    __syncthreads();
    if (tid == 0) {
        int acc = 0, nt = 0;
        for (int t = 0; t < T_DIM; ++t) {
            ws_i[t] = acc;
            cur[t]  = acc;
            for (int m0 = 0; m0 < cnt[t]; m0 += TM) {
                ws_i[32 + nt]  = t;
                ws_i[128 + nt] = m0;
                ++nt;
            }
            acc += cnt[t];
        }
        ws_i[16] = acc;
        ws_i[31] = nt;
    }
    __syncthreads();
    for (int n = tid; n < B; n += 256) {
        const int p = atomicAdd(&cur[tasks[n]], 1);
        ws_i[256 + p] = n;
    }
}

__global__ __launch_bounds__(256) void gemm_partial_kernel(
    const float* __restrict__ x,
    const float* __restrict__ weights,
    const int*   __restrict__ ws_i,
    float*       __restrict__ ws_f) {
    const int ntiles = ws_i[31];
    const int tile   = blockIdx.y;
    if (tile >= ntiles) return;
    const int t    = ws_i[32 + tile];
    const int m0   = ws_i[128 + tile];
    const int base = ws_i[t];
    const int cntt = ws_i[t + 1] - ws_i[t];
    const int k0   = blockIdx.x * KCH;
    const int cb   = blockIdx.z * 64;
    const int* idx = ws_i + 256;

    const int tid  = threadIdx.x;
    const int wid  = tid >> 6;
    const int lane = tid & 63;
    const int mw   = wid & 1;        // sample half: rows mw*16..+15
    const int nh   = wid >> 1;       // channel half within cb: +nh*32

    const int arow = mw * 16 + (lane & 15);
    const int kl   = (lane >> 4) * 8;          // k offset within 32-k step

    const int  r   = m0 + arow;
    const bool rv  = (r < cntt);
    const int  n   = idx[base + (rv ? r : 0)];   // clamped; invalid rows discarded later

    const float* xrow = x + (size_t)n * D_DIM + k0;
    const float* wrow = weights + ((size_t)t * C_DIM + cb + nh * 32 + (lane & 15)) * D_DIM + k0;

    f32x4 acc0 = {0.f, 0.f, 0.f, 0.f};
    f32x4 acc1 = {0.f, 0.f, 0.f, 0.f};

    #pragma unroll
    for (int ks = 0; ks < KCH / 32; ++ks) {
        const int ko = ks * 32 + kl;
        const float4 a0  = *reinterpret_cast<const float4*>(xrow + ko);
        const float4 a1  = *reinterpret_cast<const float4*>(xrow + ko + 4);
        const float4 b00 = *reinterpret_cast<const float4*>(wrow + ko);
        const float4 b01 = *reinterpret_cast<const float4*>(wrow + ko + 4);
        const float4 b10 = *reinterpret_cast<const float4*>(wrow + 16 * D_DIM + ko);
        const float4 b11 = *reinterpret_cast<const float4*>(wrow + 16 * D_DIM + ko + 4);
        const bf16x8 A  = cvt8(a0, a1);
        const bf16x8 B0 = cvt8(b00, b01);
        const bf16x8 B1 = cvt8(b10, b11);
        acc0 = __builtin_amdgcn_mfma_f32_16x16x32_bf16(A, B0, acc0, 0, 0, 0);
        acc1 = __builtin_amdgcn_mfma_f32_16x16x32_bf16(A, B1, acc1, 0, 0, 0);
    }

    // Store partial tile (32 rows x 64 cols) to disjoint slot. C/D layout:
    // col=lane&15 within frag, row=(lane>>4)*4+reg (m89-verified).
    float* pbase = ws_f + ((size_t)(tile * KSPLIT + blockIdx.x) * 2 + blockIdx.z) * (TM * 64);
    const int q  = lane >> 4;
    const int lc = nh * 32 + (lane & 15);
    #pragma unroll
    for (int reg = 0; reg < 4; ++reg) {
        const int lr = mw * 16 + q * 4 + reg;
        pbase[lr * 64 + lc]      = acc0[reg];
        pbase[lr * 64 + lc + 16] = acc1[reg];
    }
}

__global__ __launch_bounds__(256) void reduce_kernel(
    const float* __restrict__ biases,
    const int*   __restrict__ ws_i,
    const float* __restrict__ ws_f,
    float*       __restrict__ out) {
    const int ntiles = ws_i[31];
    const int tile   = blockIdx.x;
    if (tile >= ntiles) return;
    const int t    = ws_i[32 + tile];
    const int m0   = ws_i[128 + tile];
    const int base = ws_i[t];
    const int cntt = ws_i[t + 1] - ws_i[t];
    const int cbz  = blockIdx.y;
    const int cb   = cbz * 64;
    const int* idx = ws_i + 256;

    const float* pbase = ws_f + ((size_t)(tile * KSPLIT) * 2 + cbz) * (TM * 64);
    const int tid = threadIdx.x;

    #pragma unroll
    for (int j = 0; j < 2; ++j) {
        const int f   = tid + j * 256;    // 0..511 over 32 rows x 16 float4
        const int lr  = f >> 4;
        const int lc4 = f & 15;
        const int rr  = m0 + lr;
        if (rr >= cntt) continue;
        f32x4 s = *reinterpret_cast<const f32x4*>(biases + t * C_DIM + cb + lc4 * 4);
        #pragma unroll
        for (int k = 0; k < KSPLIT; ++k) {
            s += *reinterpret_cast<const f32x4*>(pbase + (size_t)k * 2 * (TM * 64) + lr * 64 + lc4 * 4);
        }
        const int n = idx[base + rr];
        *reinterpret_cast<f32x4*>(out + (size_t)n * C_DIM + cb + lc4 * 4) = s;
    }
}

extern "C" void kernel_launch(void* const* d_in, const int* in_sizes, int n_in,
                              void* d_out, int out_size, void* d_ws, size_t ws_size,
                              hipStream_t stream) {
    const float* x       = (const float*)d_in[0];
    const int*   tasks   = (const int*)d_in[1];
    const float* weights = (const float*)d_in[2];
    const float* biases  = (const float*)d_in[3];
    float*       out     = (float*)d_out;
    const int B = in_sizes[1];

    int*   ws_i = (int*)d_ws;
    float* ws_f = (float*)((char*)d_ws + 16384);

    prep_kernel<<<1, 256, 0, stream>>>(tasks, B, ws_i);

    dim3 grid_g(KSPLIT, MAX_TILES, 2);
    gemm_partial_kernel<<<grid_g, 256, 0, stream>>>(x, weights, ws_i, ws_f);

    dim3 grid_r(MAX_TILES, 2);
    reduce_kernel<<<grid_r, 256, 0, stream>>>(biases, ws_i, ws_f, out);
}

// Round 5
// 23.191 us; speedup vs baseline: 1.4705x; 1.4705x over previous
//
#include <hip/hip_runtime.h>
#include <hip/hip_bf16.h>

// TaskSpecificReadout: out[n,c] = sum_d x[n,d] * W[tasks[n],c,d] + b[tasks[n],c]
// B=2048, D=1024, T=16, C=128.
// Round 5: SINGLE fused kernel. No workspace, no atomics, no prep/reduce
// launches. Each block re-derives its task's sample list from tasks[] (8 KB)
// via ballot-free shfl-scan compaction, then does a (32-sample x 32-channel)
// bf16-MFMA tile with split-K=8 ACROSS the block's 8 waves, combines partials
// in LDS, and writes each out element exactly once (+bias). Deterministic by
// construction: pure function of inputs, single writer per element.

constexpr int D_DIM = 1024;
constexpr int C_DIM = 128;
constexpr int SLOTS = 8;     // sample tiles of 32 per task (covers up to 256/task)

typedef __attribute__((ext_vector_type(8))) short bf16x8;
typedef __attribute__((ext_vector_type(4))) float f32x4;

__device__ inline short f2bf(float f) {
    union { __hip_bfloat16 h; short s; } cv;
    cv.h = __float2bfloat16(f);
    return cv.s;
}

__device__ inline bf16x8 cvt8(float4 a, float4 b) {
    bf16x8 r;
    r[0] = f2bf(a.x); r[1] = f2bf(a.y); r[2] = f2bf(a.z); r[3] = f2bf(a.w);
    r[4] = f2bf(b.x); r[5] = f2bf(b.y); r[6] = f2bf(b.z); r[7] = f2bf(b.w);
    return r;
}

__global__ __launch_bounds__(512, 4) void fused_readout_kernel(
    const float* __restrict__ x,        // [B, D]
    const int*   __restrict__ tasks,    // [B]  (B == 2048)
    const float* __restrict__ weights,  // [T, C, D]
    const float* __restrict__ biases,   // [T, C]
    float*       __restrict__ out) {    // [B, C]
    const int cq   = blockIdx.x;   // channel quarter: cols [cq*32, cq*32+32)
    const int slot = blockIdx.y;   // sample tile within task: rows [slot*32, +32)
    const int t    = blockIdx.z;   // task

    __shared__ int   list[256];    // ordered sample indices for task t
    __shared__ int   wtot[8];
    __shared__ int   woff[9];
    __shared__ f32x4 red[32 * 64]; // 8 waves x (2mf x 2nf) x 64 lanes partials

    const int tid  = threadIdx.x;  // 0..511
    const int lane = tid & 63;
    const int w    = tid >> 6;     // wave 0..7

    // ---- per-block bucketing: compact indices of samples with tasks[n]==t ----
    const int4 tv = reinterpret_cast<const int4*>(tasks)[tid];  // n = tid*4 .. +3
    const int b0 = (tv.x == t), b1 = (tv.y == t), b2 = (tv.z == t), b3 = (tv.w == t);
    const int my = b0 + b1 + b2 + b3;
    int scan = my;                               // wave-inclusive scan
    #pragma unroll
    for (int d = 1; d < 64; d <<= 1) {
        int v = __shfl_up(scan, d);
        if (lane >= d) scan += v;
    }
    if (lane == 63) wtot[w] = scan;
    __syncthreads();
    if (tid == 0) {
        int a = 0;
        #pragma unroll
        for (int i = 0; i < 8; ++i) { woff[i] = a; a += wtot[i]; }
        woff[8] = a;
    }
    __syncthreads();
    const int cnt_t = woff[8];
    const int valid = cnt_t - slot * 32;   // rows this block owns: [0, min(valid,32))
    if (valid <= 0) return;                // uniform across block

    int off = woff[w] + scan - my;         // exclusive offset, global n-order
    const int n0 = tid * 4;
    if (b0) { if (off < 256) list[off] = n0;     ++off; }
    if (b1) { if (off < 256) list[off] = n0 + 1; ++off; }
    if (b2) { if (off < 256) list[off] = n0 + 2; ++off; }
    if (b3) { if (off < 256) list[off] = n0 + 3; ++off; }
    __syncthreads();

    // ---- GEMM: wave w covers k in [w*128, w*128+128) ----
    const int c15 = lane & 15;
    const int kl  = (lane >> 4) * 8;
    const int k0  = w * 128;
    const int lim = (cnt_t < 256 ? cnt_t : 256) - 1;

    const float* xrow[2];
    #pragma unroll
    for (int mf = 0; mf < 2; ++mf) {
        int pos = slot * 32 + mf * 16 + c15;
        pos = pos > lim ? lim : pos;           // clamp; invalid rows dropped later
        xrow[mf] = x + (size_t)list[pos] * D_DIM + k0;
    }
    const float* wrow = weights + ((size_t)t * C_DIM + cq * 32 + c15) * D_DIM + k0;

    f32x4 acc[2][2] = {};
    #pragma unroll
    for (int ks = 0; ks < 4; ++ks) {
        const int ko = ks * 32 + kl;
        bf16x8 A[2], Bf[2];
        #pragma unroll
        for (int mf = 0; mf < 2; ++mf) {
            const float4 a0 = *reinterpret_cast<const float4*>(xrow[mf] + ko);
            const float4 a1 = *reinterpret_cast<const float4*>(xrow[mf] + ko + 4);
            A[mf] = cvt8(a0, a1);
        }
        #pragma unroll
        for (int nf = 0; nf < 2; ++nf) {
            const float4 w0 = *reinterpret_cast<const float4*>(wrow + nf * 16 * D_DIM + ko);
            const float4 w1 = *reinterpret_cast<const float4*>(wrow + nf * 16 * D_DIM + ko + 4);
            Bf[nf] = cvt8(w0, w1);
        }
        #pragma unroll
        for (int mf = 0; mf < 2; ++mf)
            #pragma unroll
            for (int nf = 0; nf < 2; ++nf)
                acc[mf][nf] = __builtin_amdgcn_mfma_f32_16x16x32_bf16(A[mf], Bf[nf], acc[mf][nf], 0, 0, 0);
    }

    // ---- partials -> LDS (16B/lane contiguous: conflict-free phases) ----
    #pragma unroll
    for (int mf = 0; mf < 2; ++mf)
        #pragma unroll
        for (int nf = 0; nf < 2; ++nf)
            red[(w * 4 + mf * 2 + nf) * 64 + lane] = acc[mf][nf];
    __syncthreads();

    // ---- reduce across 8 waves + bias -> out (each thread: 2 adjacent cols) ----
    const int o   = tid * 2;        // output index in 32x32 tile
    const int r   = o >> 5;         // local row 0..31
    const int c   = o & 31;         // local col (even)
    const int mf  = r >> 4;
    const int q   = (r >> 2) & 3;
    const int reg = r & 3;
    const int nf  = c >> 4;
    const float* rf = reinterpret_cast<const float*>(red);
    float s0 = 0.f, s1 = 0.f;
    #pragma unroll
    for (int ww = 0; ww < 8; ++ww) {
        const int base = ((ww * 4 + mf * 2 + nf) * 64 + q * 16 + (c & 15)) * 4 + reg;
        s0 += rf[base];
        s1 += rf[base + 4];
    }
    if (r < valid) {
        const int n  = list[slot * 32 + r];
        const int cc = cq * 32 + c;
        float2 v;
        v.x = s0 + biases[t * C_DIM + cc];
        v.y = s1 + biases[t * C_DIM + cc + 1];
        *reinterpret_cast<float2*>(out + (size_t)n * C_DIM + cc) = v;
    }
}

extern "C" void kernel_launch(void* const* d_in, const int* in_sizes, int n_in,
                              void* d_out, int out_size, void* d_ws, size_t ws_size,
                              hipStream_t stream) {
    const float* x       = (const float*)d_in[0];
    const int*   tasks   = (const int*)d_in[1];
    const float* weights = (const float*)d_in[2];
    const float* biases  = (const float*)d_in[3];
    float*       out     = (float*)d_out;

    dim3 grid(C_DIM / 32, SLOTS, 16);   // 4 x 8 x 16 = 512 blocks
    fused_readout_kernel<<<grid, 512, 0, stream>>>(x, tasks, weights, biases, out);
}

// Round 6
// 16.618 us; speedup vs baseline: 2.0521x; 1.3955x over previous
//
#include <hip/hip_runtime.h>
#include <hip/hip_bf16.h>

// TaskSpecificReadout: out[n,c] = sum_d x[n,d] * W[tasks[n],c,d] + b[tasks[n],c]
// B=2048, D=1024, T=16, C=128.
// Round 6: single fused kernel (R5 structure) with COALESCED LDS staging.
//   - per-block bucketing via shfl-scan compaction (proven in R5)
//   - K looped in 4 chunks of 256 floats; all 512 threads cooperatively stream
//     32 x-rows + 32 W-rows as coalesced float4, cvt fp32->bf16, ds_write to a
//     padded LDS tile; next chunk's loads issued before the barrier (T14).
//   - wave w MFMAs its 32-k slice of each staged chunk (split-K=8 in-block)
//   - cross-wave reduce through LDS (aliases staging buffer) + bias -> out,
//     each element written exactly once. No atomics, no workspace.

constexpr int D_DIM = 1024;
constexpr int C_DIM = 128;
constexpr int SLOTS = 8;          // sample tiles of 32 per task
constexpr int CHUNK = 256;        // floats per staged K chunk
constexpr int LROW  = CHUNK + 8;  // shorts per LDS row (264; 528B stride)

typedef __attribute__((ext_vector_type(8))) short bf16x8;
typedef __attribute__((ext_vector_type(4))) float f32x4;
typedef __attribute__((ext_vector_type(4))) short s16x4;

__device__ inline short f2bf(float f) {
    union { __hip_bfloat16 h; short s; } cv;
    cv.h = __float2bfloat16(f);
    return cv.s;
}

__global__ __launch_bounds__(512, 2) void fused_readout_kernel(
    const float* __restrict__ x,        // [B, D]
    const int*   __restrict__ tasks,    // [B]  (B == 2048)
    const float* __restrict__ weights,  // [T, C, D]
    const float* __restrict__ biases,   // [T, C]
    float*       __restrict__ out) {    // [B, C]
    const int cq   = blockIdx.x;   // channel quarter: cols [cq*32, +32)
    const int slot = blockIdx.y;   // sample tile within task
    const int t    = blockIdx.z;   // task

    __shared__ int list[256];
    __shared__ int wtot[8];
    __shared__ int woff[9];
    __shared__ __align__(16) char smem[64 * LROW * 2];  // 33792 B
    short* st  = reinterpret_cast<short*>(smem);        // st[row*LROW + k]
    f32x4* red = reinterpret_cast<f32x4*>(smem);        // aliases st (after barrier)

    const int tid  = threadIdx.x;  // 0..511
    const int lane = tid & 63;
    const int w    = tid >> 6;     // wave 0..7

    // ---- bucketing: compact indices of samples with tasks[n]==t (R5) ----
    const int4 tv = reinterpret_cast<const int4*>(tasks)[tid];
    const int b0 = (tv.x == t), b1 = (tv.y == t), b2 = (tv.z == t), b3 = (tv.w == t);
    const int my = b0 + b1 + b2 + b3;
    int scan = my;
    #pragma unroll
    for (int d = 1; d < 64; d <<= 1) {
        int v = __shfl_up(scan, d);
        if (lane >= d) scan += v;
    }
    if (lane == 63) wtot[w] = scan;
    __syncthreads();
    if (tid == 0) {
        int a = 0;
        #pragma unroll
        for (int i = 0; i < 8; ++i) { woff[i] = a; a += wtot[i]; }
        woff[8] = a;
    }
    __syncthreads();
    const int cnt_t = woff[8];
    const int valid = cnt_t - slot * 32;
    if (valid <= 0) return;                // uniform across block

    int off = woff[w] + scan - my;
    const int n0 = tid * 4;
    if (b0) { if (off < 256) list[off] = n0;     ++off; }
    if (b1) { if (off < 256) list[off] = n0 + 1; ++off; }
    if (b2) { if (off < 256) list[off] = n0 + 2; ++off; }
    if (b3) { if (off < 256) list[off] = n0 + 3; ++off; }
    __syncthreads();

    // ---- staging coords: 8 float4/thread/chunk, coalesced along k ----
    // flat idx = tid + i*512 -> row = idx>>6 (0..63), col4 = idx&63.
    // rows 0..31: x rows (list), rows 32..63: W channels cq*32 + (row-32).
    const int lim = (cnt_t < 256 ? cnt_t : 256) - 1;
    const float* src[8];
    #pragma unroll
    for (int i = 0; i < 8; ++i) {
        const int idx  = tid + i * 512;
        const int row  = idx >> 6;
        const int col4 = idx & 63;
        const float* p;
        if (row < 32) {
            int pos = slot * 32 + row;
            pos = pos > lim ? lim : pos;   // clamp; invalid rows dropped in epilogue
            p = x + (size_t)list[pos] * D_DIM;
        } else {
            p = weights + ((size_t)t * C_DIM + cq * 32 + (row - 32)) * D_DIM;
        }
        src[i] = p + col4 * 4;
    }

    const int c15 = lane & 15;
    const int kl8 = (lane >> 4) * 8;
    const int ko  = w * 32 + kl8;          // this wave's k-slice within a chunk

    f32x4 acc[2][2] = {};

    float4 rg[8];
    #pragma unroll
    for (int i = 0; i < 8; ++i) rg[i] = *reinterpret_cast<const float4*>(src[i]);

    #pragma unroll
    for (int cc = 0; cc < 4; ++cc) {
        __syncthreads();   // LDS free (prev chunk's MFMA reads done)
        #pragma unroll
        for (int i = 0; i < 8; ++i) {
            const int idx  = tid + i * 512;
            const int row  = idx >> 6;
            const int col4 = idx & 63;
            s16x4 v;
            v[0] = f2bf(rg[i].x); v[1] = f2bf(rg[i].y);
            v[2] = f2bf(rg[i].z); v[3] = f2bf(rg[i].w);
            *reinterpret_cast<s16x4*>(&st[row * LROW + col4 * 4]) = v;
        }
        if (cc < 3) {      // issue next chunk's loads early (hide under barrier+MFMA)
            #pragma unroll
            for (int i = 0; i < 8; ++i)
                rg[i] = *reinterpret_cast<const float4*>(src[i] + (cc + 1) * CHUNK);
        }
        __syncthreads();   // staged chunk visible
        const bf16x8 A0 = *reinterpret_cast<const bf16x8*>(&st[(c15     ) * LROW + ko]);
        const bf16x8 A1 = *reinterpret_cast<const bf16x8*>(&st[(16 + c15) * LROW + ko]);
        const bf16x8 B0 = *reinterpret_cast<const bf16x8*>(&st[(32 + c15) * LROW + ko]);
        const bf16x8 B1 = *reinterpret_cast<const bf16x8*>(&st[(48 + c15) * LROW + ko]);
        acc[0][0] = __builtin_amdgcn_mfma_f32_16x16x32_bf16(A0, B0, acc[0][0], 0, 0, 0);
        acc[0][1] = __builtin_amdgcn_mfma_f32_16x16x32_bf16(A0, B1, acc[0][1], 0, 0, 0);
        acc[1][0] = __builtin_amdgcn_mfma_f32_16x16x32_bf16(A1, B0, acc[1][0], 0, 0, 0);
        acc[1][1] = __builtin_amdgcn_mfma_f32_16x16x32_bf16(A1, B1, acc[1][1], 0, 0, 0);
    }

    __syncthreads();       // before reusing st as reduce buffer

    // ---- partials -> LDS ----
    #pragma unroll
    for (int mf = 0; mf < 2; ++mf)
        #pragma unroll
        for (int nf = 0; nf < 2; ++nf)
            red[(w * 4 + mf * 2 + nf) * 64 + lane] = acc[mf][nf];
    __syncthreads();

    // ---- reduce across 8 waves + bias -> out (2 adjacent cols/thread) ----
    const int o   = tid * 2;
    const int r   = o >> 5;
    const int c   = o & 31;
    const int mf  = r >> 4;
    const int q   = (r >> 2) & 3;
    const int reg = r & 3;
    const int nf  = c >> 4;
    const float* rf = reinterpret_cast<const float*>(red);
    float s0 = 0.f, s1 = 0.f;
    #pragma unroll
    for (int ww = 0; ww < 8; ++ww) {
        const int base = ((ww * 4 + mf * 2 + nf) * 64 + q * 16 + (c & 15)) * 4 + reg;
        s0 += rf[base];
        s1 += rf[base + 4];
    }
    if (r < valid) {
        const int n  = list[slot * 32 + r];
        const int cc = cq * 32 + c;
        float2 v;
        v.x = s0 + biases[t * C_DIM + cc];
        v.y = s1 + biases[t * C_DIM + cc + 1];
        *reinterpret_cast<float2*>(out + (size_t)n * C_DIM + cc) = v;
    }
}

extern "C" void kernel_launch(void* const* d_in, const int* in_sizes, int n_in,
                              void* d_out, int out_size, void* d_ws, size_t ws_size,
                              hipStream_t stream) {
    const float* x       = (const float*)d_in[0];
    const int*   tasks   = (const int*)d_in[1];
    const float* weights = (const float*)d_in[2];
    const float* biases  = (const float*)d_in[3];
    float*       out     = (float*)d_out;

    dim3 grid(C_DIM / 32, SLOTS, 16);   // 4 x 8 x 16 = 512 blocks
    fused_readout_kernel<<<grid, 512, 0, stream>>>(x, tasks, weights, biases, out);
}

// Round 7
// 13.123 us; speedup vs baseline: 2.5987x; 1.2663x over previous
//
#include <hip/hip_runtime.h>
#include <hip/hip_bf16.h>

// TaskSpecificReadout: out[n,c] = sum_d x[n,d] * W[tasks[n],c,d] + b[tasks[n],c]
// B=2048, D=1024, T=16, C=128.
// Round 7: R6 + (a) XCD-aware 1-D block mapping: id%8 == task%8 so all blocks
// sharing a task's W tile and x rows land on ONE XCD -> re-reads are L2-local
// (2 MB working set < 4 MB per-XCD L2); (b) double-buffered LDS staging:
// 1 barrier/chunk, next chunk's ds_writes overlap current chunk's MFMA.
// Still: single kernel, no atomics, no workspace, single writer per output.

constexpr int D_DIM = 1024;
constexpr int C_DIM = 128;
constexpr int SLOTS = 8;          // sample tiles of 32 per task (covers <=256)
constexpr int CHUNK = 256;        // floats per staged K chunk
constexpr int LROW  = CHUNK + 8;  // shorts per LDS row (264; 528B stride)

typedef __attribute__((ext_vector_type(8))) short bf16x8;
typedef __attribute__((ext_vector_type(4))) float f32x4;
typedef __attribute__((ext_vector_type(4))) short s16x4;

__device__ inline short f2bf(float f) {
    union { __hip_bfloat16 h; short s; } cv;
    cv.h = __float2bfloat16(f);
    return cv.s;
}

__global__ __launch_bounds__(512, 2) void fused_readout_kernel(
    const float* __restrict__ x,        // [B, D]
    const int*   __restrict__ tasks,    // [B]  (B == 2048)
    const float* __restrict__ weights,  // [T, C, D]
    const float* __restrict__ biases,   // [T, C]
    float*       __restrict__ out) {    // [B, C]
    // XCD-aware decode: id%8 = t&7 (wg i -> XCD i%8 round-robin).
    // id = (t&7) + 8*(slot + 8*(cq + 4*(t>>3)))
    const int bid   = blockIdx.x;
    const int inner = bid >> 3;
    const int slot  = inner & 7;
    const int cq    = (inner >> 3) & 3;
    const int t     = (bid & 7) + ((inner >> 5) << 3);

    __shared__ int list[256];
    __shared__ int wtot[8];
    __shared__ int woff[9];
    __shared__ __align__(16) char smem[2][64 * LROW * 2];  // 2 x 33792 B
    short* buf0 = reinterpret_cast<short*>(smem[0]);
    short* buf1 = reinterpret_cast<short*>(smem[1]);
    f32x4* red  = reinterpret_cast<f32x4*>(smem[0]);       // aliases buf0

    const int tid  = threadIdx.x;  // 0..511
    const int lane = tid & 63;
    const int w    = tid >> 6;     // wave 0..7

    // ---- bucketing: compact indices of samples with tasks[n]==t ----
    const int4 tv = reinterpret_cast<const int4*>(tasks)[tid];
    const int b0 = (tv.x == t), b1 = (tv.y == t), b2 = (tv.z == t), b3 = (tv.w == t);
    const int my = b0 + b1 + b2 + b3;
    int scan = my;
    #pragma unroll
    for (int d = 1; d < 64; d <<= 1) {
        int v = __shfl_up(scan, d);
        if (lane >= d) scan += v;
    }
    if (lane == 63) wtot[w] = scan;
    __syncthreads();
    if (tid == 0) {
        int a = 0;
        #pragma unroll
        for (int i = 0; i < 8; ++i) { woff[i] = a; a += wtot[i]; }
        woff[8] = a;
    }
    __syncthreads();
    const int cnt_t = woff[8];
    const int valid = cnt_t - slot * 32;
    if (valid <= 0) return;                // uniform across block

    int off = woff[w] + scan - my;
    const int n0 = tid * 4;
    if (b0) { if (off < 256) list[off] = n0;     ++off; }
    if (b1) { if (off < 256) list[off] = n0 + 1; ++off; }
    if (b2) { if (off < 256) list[off] = n0 + 2; ++off; }
    if (b3) { if (off < 256) list[off] = n0 + 3; ++off; }
    __syncthreads();

    // ---- staging coords: 8 float4/thread/chunk, coalesced along k ----
    const int lim = (cnt_t < 256 ? cnt_t : 256) - 1;
    const float* src[8];
    #pragma unroll
    for (int i = 0; i < 8; ++i) {
        const int idx  = tid + i * 512;
        const int row  = idx >> 6;
        const int col4 = idx & 63;
        const float* p;
        if (row < 32) {
            int pos = slot * 32 + row;
            pos = pos > lim ? lim : pos;   // clamp; invalid rows dropped in epilogue
            p = x + (size_t)list[pos] * D_DIM;
        } else {
            p = weights + ((size_t)t * C_DIM + cq * 32 + (row - 32)) * D_DIM;
        }
        src[i] = p + col4 * 4;
    }

    const int c15 = lane & 15;
    const int ko  = w * 32 + (lane >> 4) * 8;   // this wave's k-slice in a chunk

    f32x4 acc[2][2] = {};

    float4 rg[8];
    #pragma unroll
    for (int i = 0; i < 8; ++i) rg[i] = *reinterpret_cast<const float4*>(src[i]);

    #pragma unroll
    for (int cc = 0; cc < 4; ++cc) {
        short* st = (cc & 1) ? buf1 : buf0;
        // write staged chunk (overlaps other waves' MFMA of chunk cc-1)
        #pragma unroll
        for (int i = 0; i < 8; ++i) {
            const int idx  = tid + i * 512;
            const int row  = idx >> 6;
            const int col4 = idx & 63;
            s16x4 v;
            v[0] = f2bf(rg[i].x); v[1] = f2bf(rg[i].y);
            v[2] = f2bf(rg[i].z); v[3] = f2bf(rg[i].w);
            *reinterpret_cast<s16x4*>(&st[row * LROW + col4 * 4]) = v;
        }
        if (cc < 3) {      // issue next chunk's loads early
            #pragma unroll
            for (int i = 0; i < 8; ++i)
                rg[i] = *reinterpret_cast<const float4*>(src[i] + (cc + 1) * CHUNK);
        }
        __syncthreads();   // chunk cc visible; all waves done MFMA cc-1
        const bf16x8 A0 = *reinterpret_cast<const bf16x8*>(&st[(c15     ) * LROW + ko]);
        const bf16x8 A1 = *reinterpret_cast<const bf16x8*>(&st[(16 + c15) * LROW + ko]);
        const bf16x8 B0 = *reinterpret_cast<const bf16x8*>(&st[(32 + c15) * LROW + ko]);
        const bf16x8 B1 = *reinterpret_cast<const bf16x8*>(&st[(48 + c15) * LROW + ko]);
        acc[0][0] = __builtin_amdgcn_mfma_f32_16x16x32_bf16(A0, B0, acc[0][0], 0, 0, 0);
        acc[0][1] = __builtin_amdgcn_mfma_f32_16x16x32_bf16(A0, B1, acc[0][1], 0, 0, 0);
        acc[1][0] = __builtin_amdgcn_mfma_f32_16x16x32_bf16(A1, B0, acc[1][0], 0, 0, 0);
        acc[1][1] = __builtin_amdgcn_mfma_f32_16x16x32_bf16(A1, B1, acc[1][1], 0, 0, 0);
    }

    // ---- partials -> LDS (red aliases buf0; last buf0 reader was MFMA cc=2,
    //      fenced by the cc=3 barrier; each wave writes after its own MFMA3) ----
    #pragma unroll
    for (int mf = 0; mf < 2; ++mf)
        #pragma unroll
        for (int nf = 0; nf < 2; ++nf)
            red[(w * 4 + mf * 2 + nf) * 64 + lane] = acc[mf][nf];
    __syncthreads();

    // ---- reduce across 8 waves + bias -> out (2 adjacent cols/thread) ----
    const int o   = tid * 2;
    const int r   = o >> 5;
    const int c   = o & 31;
    const int mf  = r >> 4;
    const int q   = (r >> 2) & 3;
    const int reg = r & 3;
    const int nf  = c >> 4;
    const float* rf = reinterpret_cast<const float*>(red);
    float s0 = 0.f, s1 = 0.f;
    #pragma unroll
    for (int ww = 0; ww < 8; ++ww) {
        const int base = ((ww * 4 + mf * 2 + nf) * 64 + q * 16 + (c & 15)) * 4 + reg;
        s0 += rf[base];
        s1 += rf[base + 4];
    }
    if (r < valid) {
        const int n  = list[slot * 32 + r];
        const int cc = cq * 32 + c;
        float2 v;
        v.x = s0 + biases[t * C_DIM + cc];
        v.y = s1 + biases[t * C_DIM + cc + 1];
        *reinterpret_cast<float2*>(out + (size_t)n * C_DIM + cc) = v;
    }
}

extern "C" void kernel_launch(void* const* d_in, const int* in_sizes, int n_in,
                              void* d_out, int out_size, void* d_ws, size_t ws_size,
                              hipStream_t stream) {
    const float* x       = (const float*)d_in[0];
    const int*   tasks   = (const int*)d_in[1];
    const float* weights = (const float*)d_in[2];
    const float* biases  = (const float*)d_in[3];
    float*       out     = (float*)d_out;

    fused_readout_kernel<<<512, 512, 0, stream>>>(x, tasks, weights, biases, out);
}

// Round 8
// 12.753 us; speedup vs baseline: 2.6742x; 1.0290x over previous
//
#include <hip/hip_runtime.h>
#include <hip/hip_bf16.h>

// TaskSpecificReadout: out[n,c] = sum_d x[n,d] * W[tasks[n],c,d] + b[tasks[n],c]
// B=2048, D=1024, T=16, C=128.
// Round 8: R7 (XCD-aware mapping + double-buffered staging) with a shortened
// prologue critical path:
//   - W-row loads + bias load issued at kernel entry (no deps on bucketing)
//   - bucketing with 2 barriers, per-thread redundant prefix (no tid==0 serial)
//   - inactive blocks exit after barrier 1
//   - chunk-0 staging writes W rows first (x loads issued later than W's)
// Single kernel, no atomics, no workspace, single writer per output element.

constexpr int D_DIM = 1024;
constexpr int C_DIM = 128;
constexpr int CHUNK = 256;        // floats per staged K chunk
constexpr int LROW  = CHUNK + 8;  // shorts per LDS row (264; 528B stride)

typedef __attribute__((ext_vector_type(8))) short bf16x8;
typedef __attribute__((ext_vector_type(4))) float f32x4;
typedef __attribute__((ext_vector_type(4))) short s16x4;

__device__ inline short f2bf(float f) {
    union { __hip_bfloat16 h; short s; } cv;
    cv.h = __float2bfloat16(f);
    return cv.s;
}

__global__ __launch_bounds__(512, 2) void fused_readout_kernel(
    const float* __restrict__ x,        // [B, D]
    const int*   __restrict__ tasks,    // [B]  (B == 2048)
    const float* __restrict__ weights,  // [T, C, D]
    const float* __restrict__ biases,   // [T, C]
    float*       __restrict__ out) {    // [B, C]
    // XCD-aware decode: id%8 = t&7 -> all blocks of a task land on one XCD.
    const int bid   = blockIdx.x;
    const int inner = bid >> 3;
    const int slot  = inner & 7;
    const int cq    = (inner >> 3) & 3;
    const int t     = (bid & 7) + ((inner >> 5) << 3);

    __shared__ int list[256];
    __shared__ int wtot[8];
    __shared__ __align__(16) char smem[2][64 * LROW * 2];  // 2 x 33792 B
    short* buf0 = reinterpret_cast<short*>(smem[0]);
    short* buf1 = reinterpret_cast<short*>(smem[1]);
    f32x4* red  = reinterpret_cast<f32x4*>(smem[0]);       // aliases buf0

    const int tid  = threadIdx.x;  // 0..511
    const int lane = tid & 63;
    const int w    = tid >> 6;     // wave 0..7

    // ---- issue W-row loads + bias load FIRST (independent of bucketing) ----
    // flat idx = tid + i*512 -> row = w + 8i, col4 = lane.
    // i=0..3: x rows (need list); i=4..7: W rows (known now).
    const float* src[8];
    float4 rg[8];
    #pragma unroll
    for (int i = 4; i < 8; ++i) {
        src[i] = weights + ((size_t)t * C_DIM + cq * 32 + (w + 8 * i - 32)) * D_DIM + lane * 4;
        rg[i] = *reinterpret_cast<const float4*>(src[i]);
    }
    const float2 bias2 = *reinterpret_cast<const float2*>(
        biases + t * C_DIM + cq * 32 + ((tid * 2) & 31));

    // ---- bucketing: compact indices of samples with tasks[n]==t ----
    const int4 tv = reinterpret_cast<const int4*>(tasks)[tid];
    const int b0 = (tv.x == t), b1 = (tv.y == t), b2 = (tv.z == t), b3 = (tv.w == t);
    const int my = b0 + b1 + b2 + b3;
    int scan = my;
    #pragma unroll
    for (int d = 1; d < 64; d <<= 1) {
        int v = __shfl_up(scan, d);
        if (lane >= d) scan += v;
    }
    if (lane == 63) wtot[w] = scan;
    __syncthreads();                       // barrier 1
    int cnt_t = 0, pre = 0;
    #pragma unroll
    for (int i = 0; i < 8; ++i) {          // broadcast LDS reads, redundant prefix
        const int v = wtot[i];
        if (i < w) pre += v;
        cnt_t += v;
    }
    const int valid = cnt_t - slot * 32;   // uniform across block
    if (valid <= 0) return;

    int off = pre + scan - my;
    const int n0 = tid * 4;
    if (b0) { if (off < 256) list[off] = n0;     ++off; }
    if (b1) { if (off < 256) list[off] = n0 + 1; ++off; }
    if (b2) { if (off < 256) list[off] = n0 + 2; ++off; }
    if (b3) { if (off < 256) list[off] = n0 + 3; ++off; }
    __syncthreads();                       // barrier 2

    // ---- x-row sources (need list) ----
    const int lim = (cnt_t < 256 ? cnt_t : 256) - 1;
    #pragma unroll
    for (int i = 0; i < 4; ++i) {
        int pos = slot * 32 + w + 8 * i;
        pos = pos > lim ? lim : pos;       // clamp; invalid rows dropped in epilogue
        src[i] = x + (size_t)list[pos] * D_DIM + lane * 4;
        rg[i] = *reinterpret_cast<const float4*>(src[i]);
    }

    const int c15 = lane & 15;
    const int ko  = w * 32 + (lane >> 4) * 8;   // this wave's k-slice in a chunk

    f32x4 acc[2][2] = {};

    #pragma unroll
    for (int cc = 0; cc < 4; ++cc) {
        short* st = (cc & 1) ? buf1 : buf0;
        // stage W rows first (loaded earliest), then x rows
        #pragma unroll
        for (int j = 0; j < 8; ++j) {
            const int i   = (j + 4) & 7;        // 4,5,6,7,0,1,2,3
            const int row = w + 8 * i;
            s16x4 v;
            v[0] = f2bf(rg[i].x); v[1] = f2bf(rg[i].y);
            v[2] = f2bf(rg[i].z); v[3] = f2bf(rg[i].w);
            *reinterpret_cast<s16x4*>(&st[row * LROW + lane * 4]) = v;
        }
        if (cc < 3) {      // issue next chunk's loads early
            #pragma unroll
            for (int i = 0; i < 8; ++i)
                rg[i] = *reinterpret_cast<const float4*>(src[i] + (cc + 1) * CHUNK);
        }
        __syncthreads();   // chunk cc visible; all waves' MFMA cc-1 reads drained
        const bf16x8 A0 = *reinterpret_cast<const bf16x8*>(&st[(c15     ) * LROW + ko]);
        const bf16x8 A1 = *reinterpret_cast<const bf16x8*>(&st[(16 + c15) * LROW + ko]);
        const bf16x8 B0 = *reinterpret_cast<const bf16x8*>(&st[(32 + c15) * LROW + ko]);
        const bf16x8 B1 = *reinterpret_cast<const bf16x8*>(&st[(48 + c15) * LROW + ko]);
        acc[0][0] = __builtin_amdgcn_mfma_f32_16x16x32_bf16(A0, B0, acc[0][0], 0, 0, 0);
        acc[0][1] = __builtin_amdgcn_mfma_f32_16x16x32_bf16(A0, B1, acc[0][1], 0, 0, 0);
        acc[1][0] = __builtin_amdgcn_mfma_f32_16x16x32_bf16(A1, B0, acc[1][0], 0, 0, 0);
        acc[1][1] = __builtin_amdgcn_mfma_f32_16x16x32_bf16(A1, B1, acc[1][1], 0, 0, 0);
    }

    // ---- partials -> LDS (red aliases buf0; buf0's last reader MFMA cc=2
    //      drained at the cc=3 barrier; MFMA cc=3 reads buf1 only) ----
    #pragma unroll
    for (int mf = 0; mf < 2; ++mf)
        #pragma unroll
        for (int nf = 0; nf < 2; ++nf)
            red[(w * 4 + mf * 2 + nf) * 64 + lane] = acc[mf][nf];
    __syncthreads();

    // ---- reduce across 8 waves + bias -> out (2 adjacent cols/thread) ----
    const int o   = tid * 2;
    const int r   = o >> 5;
    const int c   = o & 31;
    const int mf  = r >> 4;
    const int q   = (r >> 2) & 3;
    const int reg = r & 3;
    const int nf  = c >> 4;
    const float* rf = reinterpret_cast<const float*>(red);
    float s0 = 0.f, s1 = 0.f;
    #pragma unroll
    for (int ww = 0; ww < 8; ++ww) {
        const int base = ((ww * 4 + mf * 2 + nf) * 64 + q * 16 + (c & 15)) * 4 + reg;
        s0 += rf[base];
        s1 += rf[base + 4];
    }
    if (r < valid) {
        const int n  = list[slot * 32 + r];
        const int cc = cq * 32 + c;
        float2 v;
        v.x = s0 + bias2.x;
        v.y = s1 + bias2.y;
        *reinterpret_cast<float2*>(out + (size_t)n * C_DIM + cc) = v;
    }
}

extern "C" void kernel_launch(void* const* d_in, const int* in_sizes, int n_in,
                              void* d_out, int out_size, void* d_ws, size_t ws_size,
                              hipStream_t stream) {
    const float* x       = (const float*)d_in[0];
    const int*   tasks   = (const int*)d_in[1];
    const float* weights = (const float*)d_in[2];
    const float* biases  = (const float*)d_in[3];
    float*       out     = (float*)d_out;

    fused_readout_kernel<<<512, 512, 0, stream>>>(x, tasks, weights, biases, out);
}